// Round 5
// baseline (296.676 us; speedup 1.0000x reference)
//
#include <hip/hip_runtime.h>

#define H 160
#define W 160
#define HW 25600
#define BB 2
#define CC 3
#define LL 72
#define NKEYS 3000
#define NKPAD 3008
#define NT 94          // key tiles of 32
#define NG 47          // groups of 2 tiles
#define NPIX (BB * HW) // 51200

// rigorous split-bf16 error window: |approx-exact| <= ~2.2e-5 * S_p * kmax
#define CERR 3e-5f
#define ABSG 1e-3f

typedef __attribute__((ext_vector_type(8))) short bf8v;   // 8 bf16 (4 VGPR)
typedef __attribute__((ext_vector_type(16))) float f16v;  // MFMA 32x32 acc

union FU { uint4 u4; bf8v v; };

// ws layout (bytes):
//   [0..3]  count   [4..7] kmax bits
//   [1024 .. +962560)      kfrag: NT*5ksteps*2splits*64lanes*16B
//   [963584 .. +204800)    cleanup list (u32 pixel ids)
//   [1168384 .. +204800)   idx_buf (i32 per pixel)
#define WS_KFRAG 1024
#define WS_LIST  963584
#define WS_IDX   1168384

__device__ inline unsigned bf16rn(float f) {  // RN-even bf16 bits (low 16)
    unsigned u = __float_as_uint(f);
    return (u + 0x7FFFu + ((u >> 16) & 1u)) >> 16;
}

// ---------- kprep: keys -> bf16 hi/lo MFMA A-fragment layout + Kmax ----------
__global__ __launch_bounds__(64) void kprep_kernel(
    const float* __restrict__ keys, unsigned* __restrict__ ctrl,
    uint4* __restrict__ kfg)
{
    const int tile = blockIdx.x;
    const int lane = threadIdx.x;
    const int key  = tile * 32 + (lane & 31);
    const int half = lane >> 5;
    const bool kv  = (key < NKEYS);
    float kmax = 0.f;
#pragma unroll
    for (int ks = 0; ks < 5; ++ks) {
        unsigned wh[4], wl[4];
#pragma unroll
        for (int j = 0; j < 4; ++j) {
            const int l0 = ks * 16 + half * 8 + 2 * j;
            float v0 = (kv && l0     < LL) ? keys[(size_t)key * LL + l0]     : 0.f;
            float v1 = (kv && l0 + 1 < LL) ? keys[(size_t)key * LL + l0 + 1] : 0.f;
            kmax = fmaxf(kmax, fmaxf(fabsf(v0), fabsf(v1)));
            unsigned h0 = bf16rn(v0), h1 = bf16rn(v1);
            float r0 = v0 - __uint_as_float(h0 << 16);
            float r1 = v1 - __uint_as_float(h1 << 16);
            wh[j] = h0 | (h1 << 16);
            wl[j] = bf16rn(r0) | (bf16rn(r1) << 16);
        }
        const int base = tile * 640 + (ks * 2) * 64 + lane;
        kfg[base]      = make_uint4(wh[0], wh[1], wh[2], wh[3]);
        kfg[base + 64] = make_uint4(wl[0], wl[1], wl[2], wl[3]);
    }
#pragma unroll
    for (int m = 32; m >= 1; m >>= 1)
        kmax = fmaxf(kmax, __shfl_xor(kmax, m));
    if (lane == 0) atomicMax(&ctrl[1], __float_as_uint(kmax));
}

// ---------------- route: 3-product bf16 MFMA + exact f32 top-2 ----------------
template<bool LAST>
__device__ inline void do_tile(const uint4* __restrict__ kb, int t, int tileIdx,
                               const FU* __restrict__ qh, const FU* __restrict__ ql,
                               int lane, int hb, float& b1, float& b2, int& bi)
{
    f16v acc;
#pragma unroll
    for (int r = 0; r < 16; ++r) acc[r] = 0.f;
#pragma unroll
    for (int ks = 0; ks < 5; ++ks) {
        FU kh, kl;
        kh.u4 = kb[(t * 5 + ks) * 128 + lane];
        kl.u4 = kb[(t * 5 + ks) * 128 + 64 + lane];
        acc = __builtin_amdgcn_mfma_f32_32x32x16_bf16(kh.v, qh[ks].v, acc, 0, 0, 0);
        acc = __builtin_amdgcn_mfma_f32_32x32x16_bf16(kh.v, ql[ks].v, acc, 0, 0, 0);
        acc = __builtin_amdgcn_mfma_f32_32x32x16_bf16(kl.v, qh[ks].v, acc, 0, 0, 0);
    }
    const int kb0 = tileIdx * 32 + hb;
    const int NR = LAST ? 12 : 16;   // last tile rows >=24 are pad keys
#pragma unroll
    for (int r = 0; r < NR; ++r) {
        const float s = acc[r];
        const int key = kb0 + ((r & 3) + 8 * (r >> 2));
        const bool gt = (s > b1);           // keys per lane are ascending
        b2 = fmaxf(b2, fminf(s, b1));
        b1 = fmaxf(b1, s);
        bi = gt ? key : bi;
    }
}

// grid = 400 blocks x 256 (4 waves, each wave = 32 pixels across all keys)
__global__ __launch_bounds__(256) void route_kernel(
    const float* __restrict__ queries,
    const uint4* __restrict__ kfg,
    unsigned* __restrict__ ctrl,
    unsigned* __restrict__ list,
    int* __restrict__ idx_buf)
{
    __shared__ uint4 kbuf[2][1280];   // 40 KB

    const int tid  = threadIdx.x;
    const int lane = tid & 63;
    const int wid  = tid >> 6;
    const int hv   = lane >> 5;       // k-half
    const int hb   = 4 * hv;
    const int pbase = blockIdx.x * 128 + wid * 32;
    const int p    = pbase + (lane & 31);
    const int b    = p / HW;
    const int hw   = p - b * HW;
    const float* __restrict__ qp = queries + (size_t)b * LL * HW + hw;

    FU qh[5], ql[5];
    float Ssum = 0.f;
#pragma unroll
    for (int ks = 0; ks < 5; ++ks) {
        unsigned wh[4], wl[4];
#pragma unroll
        for (int j = 0; j < 4; ++j) {
            const int l0 = ks * 16 + hv * 8 + 2 * j;
            float v0 = (l0     < LL) ? qp[(size_t)l0 * HW]       : 0.f;
            float v1 = (l0 + 1 < LL) ? qp[(size_t)(l0 + 1) * HW] : 0.f;
            Ssum += fabsf(v0) + fabsf(v1);
            unsigned h0 = bf16rn(v0), h1 = bf16rn(v1);
            float r0 = v0 - __uint_as_float(h0 << 16);
            float r1 = v1 - __uint_as_float(h1 << 16);
            wh[j] = h0 | (h1 << 16);
            wl[j] = bf16rn(r0) | (bf16rn(r1) << 16);
        }
        qh[ks].u4 = make_uint4(wh[0], wh[1], wh[2], wh[3]);
        ql[ks].u4 = make_uint4(wl[0], wl[1], wl[2], wl[3]);
    }
    const float S_p = Ssum + __shfl_xor(Ssum, 32);
    const float kmax = __uint_as_float(ctrl[1]);

    float b1 = -3.0e38f, b2 = -3.0e38f;
    int bi = 0;

#pragma unroll
    for (int j = 0; j < 5; ++j)
        kbuf[0][tid + j * 256] = kfg[tid + j * 256];
    __syncthreads();

    for (int g = 0; g < NG; ++g) {
        const int cur = g & 1;
        if (g < NG - 1) {
#pragma unroll
            for (int j = 0; j < 5; ++j)
                kbuf[cur ^ 1][tid + j * 256] = kfg[(size_t)(g + 1) * 1280 + tid + j * 256];
        }
        const uint4* kb = kbuf[cur];
        do_tile<false>(kb, 0, 2 * g, qh, ql, lane, hb, b1, b2, bi);
        if (g == NG - 1) do_tile<true >(kb, 1, 2 * g + 1, qh, ql, lane, hb, b1, b2, bi);
        else             do_tile<false>(kb, 1, 2 * g + 1, qh, ql, lane, hb, b1, b2, bi);
        __syncthreads();
    }

    const float ob1 = __shfl_xor(b1, 32);
    const float ob2 = __shfl_xor(b2, 32);
    const int   obi = __shfl_xor(bi, 32);
    const float nb2 = fmaxf(fminf(b1, ob1), fmaxf(b2, ob2));
    const bool take = (ob1 > b1) || (ob1 == b1 && obi < bi);
    const float nb1 = fmaxf(b1, ob1);
    const int  nbi = take ? obi : bi;

    const float thr = 2.0f * (CERR * S_p * kmax + ABSG);
    const bool certain = ((nb1 - nb2) > thr);

    if ((lane & 32) == 0) {
        if (certain) idx_buf[p] = nbi;
        else { unsigned pos = atomicAdd(&ctrl[0], 1u); list[pos] = (unsigned)p; }
    }
}

// -------- cleanup: exact f32 rescore, one BLOCK per uncertain pixel --------
// grid = 2048 blocks x 256, grid-stride over the list. q staged in LDS;
// 256 threads split the 3000 keys (12 strided iterations); two-level reduce.
__global__ __launch_bounds__(256) void cleanup_kernel(
    const float* __restrict__ queries, const float* __restrict__ keys,
    const unsigned* __restrict__ ctrl, const unsigned* __restrict__ list,
    int* __restrict__ idx_buf)
{
    __shared__ float qs[LL];
    __shared__ float rbest[4];
    __shared__ int   ridx[4];

    const int tid = threadIdx.x;
    const int ln  = tid & 63;
    const int wid = tid >> 6;
    const unsigned count = ctrl[0];

    for (unsigned u = blockIdx.x; u < count; u += gridDim.x) {
        const int p  = (int)list[u];
        const int b  = p / HW;
        const int hw = p - b * HW;

        __syncthreads();   // protect qs from previous iteration's readers
        if (tid < LL)
            qs[tid] = queries[((size_t)b * LL + tid) * HW + hw];
        __syncthreads();

        float q[LL];
#pragma unroll
        for (int l = 0; l < LL; ++l) q[l] = qs[l];   // LDS broadcast reads

        float best = -3.0e38f; int bidx = 0x7FFFFFFF;
#pragma unroll
        for (int it = 0; it < 12; ++it) {
            const int n  = it * 256 + tid;
            const int nc = (n < NKEYS) ? n : (NKEYS - 1);
            const float4* __restrict__ kr = (const float4*)(keys + (size_t)nc * LL);
            float a0 = 0.f, a1 = 0.f, a2 = 0.f, a3 = 0.f;
#pragma unroll
            for (int j = 0; j < 18; ++j) {
                float4 kv = kr[j];
                a0 = fmaf(q[4 * j + 0], kv.x, a0);
                a1 = fmaf(q[4 * j + 1], kv.y, a1);
                a2 = fmaf(q[4 * j + 2], kv.z, a2);
                a3 = fmaf(q[4 * j + 3], kv.w, a3);
            }
            const float s = (a0 + a1) + (a2 + a3);
            if (n < NKEYS && (s > best || (s == best && n < bidx))) { best = s; bidx = n; }
        }
        // wave reduce (first-occurrence: ties -> smaller index)
#pragma unroll
        for (int m = 32; m >= 1; m >>= 1) {
            const float ob = __shfl_xor(best, m);
            const int   oi = __shfl_xor(bidx, m);
            if (ob > best || (ob == best && oi < bidx)) { best = ob; bidx = oi; }
        }
        if (ln == 0) { rbest[wid] = best; ridx[wid] = bidx; }
        __syncthreads();
        if (tid == 0) {
            float fb = rbest[0]; int fi = ridx[0];
#pragma unroll
            for (int wvi = 1; wvi < 4; ++wvi) {
                if (rbest[wvi] > fb || (rbest[wvi] == fb && ridx[wvi] < fi)) {
                    fb = rbest[wvi]; fi = ridx[wvi];
                }
            }
            idx_buf[p] = fi;
        }
    }
}

// ------- conv: gather + dynamic 5x5 conv + pixel shuffle -------
__global__ __launch_bounds__(256) void conv_kernel(
    const float* __restrict__ x,
    const float* __restrict__ values,
    const int* __restrict__ idx_buf,
    float* __restrict__ out)
{
    const int p  = blockIdx.x * 256 + threadIdx.x;
    const int b  = p / HW;
    const int hw = p - b * HW;
    const int h  = hw / W;
    const int w  = hw - h * W;

    const int idx = idx_buf[p];

    float patch[CC][25];
#pragma unroll
    for (int i = 0; i < 5; ++i) {
        int r = h + i - 2;
        r = (r < 0) ? -r : ((r >= H) ? (2 * H - 2 - r) : r);
#pragma unroll
        for (int j = 0; j < 5; ++j) {
            int cidx = w + j - 2;
            cidx = (cidx < 0) ? -cidx : ((cidx >= W) ? (2 * W - 2 - cidx) : cidx);
#pragma unroll
            for (int c = 0; c < CC; ++c)
                patch[c][i * 5 + j] = x[((size_t)(b * CC + c) * H + r) * W + cidx];
        }
    }

    const float* vbase = values + (size_t)idx * 400;
    float acc[CC][16];
#pragma unroll
    for (int c = 0; c < CC; ++c)
#pragma unroll
        for (int si = 0; si < 16; ++si) acc[c][si] = 0.f;

#pragma unroll
    for (int si = 0; si < 16; ++si) {
        float v[25];
#pragma unroll
        for (int kk = 0; kk < 25; ++kk) v[kk] = vbase[si * 25 + kk];
#pragma unroll
        for (int c = 0; c < CC; ++c) {
            float a = 0.f;
#pragma unroll
            for (int kk = 0; kk < 25; ++kk) a += patch[c][kk] * v[kk];
            acc[c][si] = a;
        }
    }

#pragma unroll
    for (int c = 0; c < CC; ++c) {
#pragma unroll
        for (int sy = 0; sy < 4; ++sy) {
            float4 o = make_float4(acc[c][sy * 4 + 0], acc[c][sy * 4 + 1],
                                   acc[c][sy * 4 + 2], acc[c][sy * 4 + 3]);
            size_t off = ((size_t)(b * CC + c) * (H * 4) + (h * 4 + sy)) * (size_t)(W * 4)
                         + (size_t)w * 4;
            *(float4*)(&out[off]) = o;
        }
    }
}

extern "C" void kernel_launch(void* const* d_in, const int* in_sizes, int n_in,
                              void* d_out, int out_size, void* d_ws, size_t ws_size,
                              hipStream_t stream) {
    const float* x       = (const float*)d_in[0];
    const float* queries = (const float*)d_in[1];
    const float* keys    = (const float*)d_in[2];
    const float* values  = (const float*)d_in[3];
    float* out = (float*)d_out;

    char* ws = (char*)d_ws;
    unsigned* ctrl   = (unsigned*)ws;
    uint4*    kfg    = (uint4*)(ws + WS_KFRAG);
    unsigned* list   = (unsigned*)(ws + WS_LIST);
    int*      idxb   = (int*)(ws + WS_IDX);

    hipMemsetAsync(d_ws, 0, 8, stream);
    kprep_kernel<<<NT, 64, 0, stream>>>(keys, ctrl, kfg);
    route_kernel<<<NPIX / 128, 256, 0, stream>>>(queries, kfg, ctrl, list, idxb);
    cleanup_kernel<<<2048, 256, 0, stream>>>(queries, keys, ctrl, list, idxb);
    conv_kernel<<<NPIX / 256, 256, 0, stream>>>(x, values, idxb, out);
}

// Round 6
// 150.396 us; speedup vs baseline: 1.9726x; 1.9726x over previous
//
#include <hip/hip_runtime.h>

#define H 160
#define W 160
#define HW 25600
#define BB 2
#define CC 3
#define LL 72
#define NKEYS 3000
#define NKPAD 3008
#define NT 94          // key tiles of 32
#define NG 47          // groups of 2 tiles
#define NPIX (BB * HW) // 51200

// rigorous split-bf16 error window: |approx-exact| <= ~2.2e-5 * S_p * kmax
#define CERR 3e-5f
#define ABSG 1e-3f

typedef __attribute__((ext_vector_type(8))) short bf8v;   // 8 bf16 (4 VGPR)
typedef __attribute__((ext_vector_type(16))) float f16v;  // MFMA 32x32 acc

union FU { uint4 u4; bf8v v; };

// ws layout (bytes):
//   [0..3]  count   [4..7] kmax bits
//   [1024 .. +962560)      kfrag: NT*5ksteps*2splits*64lanes*16B
//   [963584 .. +204800)    cleanup list (u32 pixel ids)
//   [1168384 .. +204800)   idx_buf (i32 per pixel)
#define WS_KFRAG 1024
#define WS_LIST  963584
#define WS_IDX   1168384

__device__ inline unsigned bf16rn(float f) {  // RN-even bf16 bits (low 16)
    unsigned u = __float_as_uint(f);
    return (u + 0x7FFFu + ((u >> 16) & 1u)) >> 16;
}

// ---------- kprep: keys -> bf16 hi/lo MFMA A-fragment layout + Kmax ----------
__global__ __launch_bounds__(64) void kprep_kernel(
    const float* __restrict__ keys, unsigned* __restrict__ ctrl,
    uint4* __restrict__ kfg)
{
    const int tile = blockIdx.x;
    const int lane = threadIdx.x;
    const int key  = tile * 32 + (lane & 31);
    const int half = lane >> 5;
    const bool kv  = (key < NKEYS);
    float kmax = 0.f;
#pragma unroll
    for (int ks = 0; ks < 5; ++ks) {
        unsigned wh[4], wl[4];
#pragma unroll
        for (int j = 0; j < 4; ++j) {
            const int l0 = ks * 16 + half * 8 + 2 * j;
            float v0 = (kv && l0     < LL) ? keys[(size_t)key * LL + l0]     : 0.f;
            float v1 = (kv && l0 + 1 < LL) ? keys[(size_t)key * LL + l0 + 1] : 0.f;
            kmax = fmaxf(kmax, fmaxf(fabsf(v0), fabsf(v1)));
            unsigned h0 = bf16rn(v0), h1 = bf16rn(v1);
            float r0 = v0 - __uint_as_float(h0 << 16);
            float r1 = v1 - __uint_as_float(h1 << 16);
            wh[j] = h0 | (h1 << 16);
            wl[j] = bf16rn(r0) | (bf16rn(r1) << 16);
        }
        const int base = tile * 640 + (ks * 2) * 64 + lane;
        kfg[base]      = make_uint4(wh[0], wh[1], wh[2], wh[3]);
        kfg[base + 64] = make_uint4(wl[0], wl[1], wl[2], wl[3]);
    }
#pragma unroll
    for (int m = 32; m >= 1; m >>= 1)
        kmax = fmaxf(kmax, __shfl_xor(kmax, m));
    if (lane == 0) atomicMax(&ctrl[1], __float_as_uint(kmax));
}

// ---------------- route: 3-product bf16 MFMA + exact f32 top-2 ----------------
template<bool LAST>
__device__ inline void do_tile(const uint4* __restrict__ kb, int t, int tileIdx,
                               const FU* __restrict__ qh, const FU* __restrict__ ql,
                               int lane, int hb, float& b1, float& b2, int& bi)
{
    f16v acc;
#pragma unroll
    for (int r = 0; r < 16; ++r) acc[r] = 0.f;
#pragma unroll
    for (int ks = 0; ks < 5; ++ks) {
        FU kh, kl;
        kh.u4 = kb[(t * 5 + ks) * 128 + lane];
        kl.u4 = kb[(t * 5 + ks) * 128 + 64 + lane];
        acc = __builtin_amdgcn_mfma_f32_32x32x16_bf16(kh.v, qh[ks].v, acc, 0, 0, 0);
        acc = __builtin_amdgcn_mfma_f32_32x32x16_bf16(kh.v, ql[ks].v, acc, 0, 0, 0);
        acc = __builtin_amdgcn_mfma_f32_32x32x16_bf16(kl.v, qh[ks].v, acc, 0, 0, 0);
    }
    const int kb0 = tileIdx * 32 + hb;
    const int NR = LAST ? 12 : 16;   // last tile rows >=24 are pad keys
#pragma unroll
    for (int r = 0; r < NR; ++r) {
        const float s = acc[r];
        const int key = kb0 + ((r & 3) + 8 * (r >> 2));
        const bool gt = (s > b1);           // keys per lane are ascending
        b2 = fmaxf(b2, fminf(s, b1));
        b1 = fmaxf(b1, s);
        bi = gt ? key : bi;
    }
}

// grid = 400 blocks x 256 (4 waves, each wave = 32 pixels across all keys)
__global__ __launch_bounds__(256) void route_kernel(
    const float* __restrict__ queries,
    const uint4* __restrict__ kfg,
    unsigned* __restrict__ ctrl,
    unsigned* __restrict__ list,
    int* __restrict__ idx_buf)
{
    __shared__ uint4 kbuf[2][1280];   // 40 KB

    const int tid  = threadIdx.x;
    const int lane = tid & 63;
    const int wid  = tid >> 6;
    const int hv   = lane >> 5;       // k-half
    const int hb   = 4 * hv;
    const int pbase = blockIdx.x * 128 + wid * 32;
    const int p    = pbase + (lane & 31);
    const int b    = p / HW;
    const int hw   = p - b * HW;
    const float* __restrict__ qp = queries + (size_t)b * LL * HW + hw;

    FU qh[5], ql[5];
    float Ssum = 0.f;
#pragma unroll
    for (int ks = 0; ks < 5; ++ks) {
        unsigned wh[4], wl[4];
#pragma unroll
        for (int j = 0; j < 4; ++j) {
            const int l0 = ks * 16 + hv * 8 + 2 * j;
            float v0 = (l0     < LL) ? qp[(size_t)l0 * HW]       : 0.f;
            float v1 = (l0 + 1 < LL) ? qp[(size_t)(l0 + 1) * HW] : 0.f;
            Ssum += fabsf(v0) + fabsf(v1);
            unsigned h0 = bf16rn(v0), h1 = bf16rn(v1);
            float r0 = v0 - __uint_as_float(h0 << 16);
            float r1 = v1 - __uint_as_float(h1 << 16);
            wh[j] = h0 | (h1 << 16);
            wl[j] = bf16rn(r0) | (bf16rn(r1) << 16);
        }
        qh[ks].u4 = make_uint4(wh[0], wh[1], wh[2], wh[3]);
        ql[ks].u4 = make_uint4(wl[0], wl[1], wl[2], wl[3]);
    }
    const float S_p = Ssum + __shfl_xor(Ssum, 32);
    const float kmax = __uint_as_float(ctrl[1]);

    float b1 = -3.0e38f, b2 = -3.0e38f;
    int bi = 0;

#pragma unroll
    for (int j = 0; j < 5; ++j)
        kbuf[0][tid + j * 256] = kfg[tid + j * 256];
    __syncthreads();

    for (int g = 0; g < NG; ++g) {
        const int cur = g & 1;
        if (g < NG - 1) {
#pragma unroll
            for (int j = 0; j < 5; ++j)
                kbuf[cur ^ 1][tid + j * 256] = kfg[(size_t)(g + 1) * 1280 + tid + j * 256];
        }
        const uint4* kb = kbuf[cur];
        do_tile<false>(kb, 0, 2 * g, qh, ql, lane, hb, b1, b2, bi);
        if (g == NG - 1) do_tile<true >(kb, 1, 2 * g + 1, qh, ql, lane, hb, b1, b2, bi);
        else             do_tile<false>(kb, 1, 2 * g + 1, qh, ql, lane, hb, b1, b2, bi);
        __syncthreads();
    }

    const float ob1 = __shfl_xor(b1, 32);
    const float ob2 = __shfl_xor(b2, 32);
    const int   obi = __shfl_xor(bi, 32);
    const float nb2 = fmaxf(fminf(b1, ob1), fmaxf(b2, ob2));
    const bool take = (ob1 > b1) || (ob1 == b1 && obi < bi);
    const float nb1 = fmaxf(b1, ob1);
    const int  nbi = take ? obi : bi;

    const float thr = 2.0f * (CERR * S_p * kmax + ABSG);
    const bool certain = ((nb1 - nb2) > thr);

    if ((lane & 32) == 0) {
        if (certain) idx_buf[p] = nbi;
        else { unsigned pos = atomicAdd(&ctrl[0], 1u); list[pos] = (unsigned)p; }
    }
}

// -------- cleanup: exact f32 rescore, one BLOCK per uncertain pixel --------
// grid = 2048 blocks x 256, grid-stride over the list. q staged in LDS then
// registers; 256 threads split the 3000 keys (12 strided iterations, NOT
// unrolled -- full unroll spilled to scratch in round 5); two-level reduce.
__global__ __launch_bounds__(256) void cleanup_kernel(
    const float* __restrict__ queries, const float* __restrict__ keys,
    const unsigned* __restrict__ ctrl, const unsigned* __restrict__ list,
    int* __restrict__ idx_buf)
{
    __shared__ float qs[LL];
    __shared__ float rbest[4];
    __shared__ int   ridx[4];

    const int tid = threadIdx.x;
    const int ln  = tid & 63;
    const int wid = tid >> 6;
    const unsigned count = ctrl[0];

    for (unsigned u = blockIdx.x; u < count; u += gridDim.x) {
        const int p  = (int)list[u];
        const int b  = p / HW;
        const int hw = p - b * HW;

        __syncthreads();   // protect qs from previous iteration's readers
        if (tid < LL)
            qs[tid] = queries[((size_t)b * LL + tid) * HW + hw];
        __syncthreads();

        float q[LL];
#pragma unroll
        for (int l = 0; l < LL; ++l) q[l] = qs[l];   // LDS broadcast reads

        float best = -3.0e38f; int bidx = 0x7FFFFFFF;
#pragma unroll 1
        for (int it = 0; it < 12; ++it) {
            const int n  = it * 256 + tid;
            const int nc = (n < NKEYS) ? n : (NKEYS - 1);
            const float4* __restrict__ kr = (const float4*)(keys + (size_t)nc * LL);
            float a0 = 0.f, a1 = 0.f, a2 = 0.f, a3 = 0.f;
#pragma unroll
            for (int j = 0; j < 18; ++j) {
                float4 kv = kr[j];
                a0 = fmaf(q[4 * j + 0], kv.x, a0);
                a1 = fmaf(q[4 * j + 1], kv.y, a1);
                a2 = fmaf(q[4 * j + 2], kv.z, a2);
                a3 = fmaf(q[4 * j + 3], kv.w, a3);
            }
            const float s = (a0 + a1) + (a2 + a3);
            if (n < NKEYS && (s > best || (s == best && n < bidx))) { best = s; bidx = n; }
        }
        // wave reduce (first-occurrence: ties -> smaller index)
#pragma unroll
        for (int m = 32; m >= 1; m >>= 1) {
            const float ob = __shfl_xor(best, m);
            const int   oi = __shfl_xor(bidx, m);
            if (ob > best || (ob == best && oi < bidx)) { best = ob; bidx = oi; }
        }
        if (ln == 0) { rbest[wid] = best; ridx[wid] = bidx; }
        __syncthreads();
        if (tid == 0) {
            float fb = rbest[0]; int fi = ridx[0];
#pragma unroll
            for (int wvi = 1; wvi < 4; ++wvi) {
                if (rbest[wvi] > fb || (rbest[wvi] == fb && ridx[wvi] < fi)) {
                    fb = rbest[wvi]; fi = ridx[wvi];
                }
            }
            idx_buf[p] = fi;
        }
    }
}

// ------- conv: gather + dynamic 5x5 conv + pixel shuffle -------
__global__ __launch_bounds__(256) void conv_kernel(
    const float* __restrict__ x,
    const float* __restrict__ values,
    const int* __restrict__ idx_buf,
    float* __restrict__ out)
{
    const int p  = blockIdx.x * 256 + threadIdx.x;
    const int b  = p / HW;
    const int hw = p - b * HW;
    const int h  = hw / W;
    const int w  = hw - h * W;

    const int idx = idx_buf[p];

    float patch[CC][25];
#pragma unroll
    for (int i = 0; i < 5; ++i) {
        int r = h + i - 2;
        r = (r < 0) ? -r : ((r >= H) ? (2 * H - 2 - r) : r);
#pragma unroll
        for (int j = 0; j < 5; ++j) {
            int cidx = w + j - 2;
            cidx = (cidx < 0) ? -cidx : ((cidx >= W) ? (2 * W - 2 - cidx) : cidx);
#pragma unroll
            for (int c = 0; c < CC; ++c)
                patch[c][i * 5 + j] = x[((size_t)(b * CC + c) * H + r) * W + cidx];
        }
    }

    const float* vbase = values + (size_t)idx * 400;
    float acc[CC][16];
#pragma unroll
    for (int c = 0; c < CC; ++c)
#pragma unroll
        for (int si = 0; si < 16; ++si) acc[c][si] = 0.f;

#pragma unroll
    for (int si = 0; si < 16; ++si) {
        float v[25];
#pragma unroll
        for (int kk = 0; kk < 25; ++kk) v[kk] = vbase[si * 25 + kk];
#pragma unroll
        for (int c = 0; c < CC; ++c) {
            float a = 0.f;
#pragma unroll
            for (int kk = 0; kk < 25; ++kk) a += patch[c][kk] * v[kk];
            acc[c][si] = a;
        }
    }

#pragma unroll
    for (int c = 0; c < CC; ++c) {
#pragma unroll
        for (int sy = 0; sy < 4; ++sy) {
            float4 o = make_float4(acc[c][sy * 4 + 0], acc[c][sy * 4 + 1],
                                   acc[c][sy * 4 + 2], acc[c][sy * 4 + 3]);
            size_t off = ((size_t)(b * CC + c) * (H * 4) + (h * 4 + sy)) * (size_t)(W * 4)
                         + (size_t)w * 4;
            *(float4*)(&out[off]) = o;
        }
    }
}

extern "C" void kernel_launch(void* const* d_in, const int* in_sizes, int n_in,
                              void* d_out, int out_size, void* d_ws, size_t ws_size,
                              hipStream_t stream) {
    const float* x       = (const float*)d_in[0];
    const float* queries = (const float*)d_in[1];
    const float* keys    = (const float*)d_in[2];
    const float* values  = (const float*)d_in[3];
    float* out = (float*)d_out;

    char* ws = (char*)d_ws;
    unsigned* ctrl   = (unsigned*)ws;
    uint4*    kfg    = (uint4*)(ws + WS_KFRAG);
    unsigned* list   = (unsigned*)(ws + WS_LIST);
    int*      idxb   = (int*)(ws + WS_IDX);

    hipMemsetAsync(d_ws, 0, 8, stream);
    kprep_kernel<<<NT, 64, 0, stream>>>(keys, ctrl, kfg);
    route_kernel<<<NPIX / 128, 256, 0, stream>>>(queries, kfg, ctrl, list, idxb);
    cleanup_kernel<<<2048, 256, 0, stream>>>(queries, keys, ctrl, list, idxb);
    conv_kernel<<<NPIX / 256, 256, 0, stream>>>(x, values, idxb, out);
}

// Round 7
// 145.754 us; speedup vs baseline: 2.0355x; 1.0318x over previous
//
#include <hip/hip_runtime.h>

#define H 160
#define W 160
#define HW 25600
#define BB 2
#define CC 3
#define LL 72
#define NKEYS 3000
#define NT 94          // key tiles of 32
#define NSPL 4         // key splits (tiles: 24,24,24,22)
#define NPIX (BB * HW) // 51200

// rigorous split-bf16 error window: |approx-exact| <= ~2.2e-5 * S_p * kmax
#define CERR 3e-5f
#define ABSG 1e-3f

typedef __attribute__((ext_vector_type(8))) short bf8v;   // 8 bf16 (4 VGPR)
typedef __attribute__((ext_vector_type(16))) float f16v;  // MFMA 32x32 acc

union FU { uint4 u4; bf8v v; };

// ws layout (bytes):
//   [0..3] count  [4..7] kmax bits
//   kfrag 94*640*16 = 962560 @ 1024
//   b1s/b2s/bis: NSPL*NPIX*4 each; thr/list/idx: NPIX*4 each
#define WS_KFRAG 1024
#define WS_B1    963584
#define WS_B2    1782784
#define WS_BI    2601984
#define WS_THR   3421184
#define WS_LIST  3625984
#define WS_IDX   3830784

__device__ inline unsigned bf16rn(float f) {  // RN-even bf16 bits (low 16)
    unsigned u = __float_as_uint(f);
    return (u + 0x7FFFu + ((u >> 16) & 1u)) >> 16;
}

// ---------- kprep: keys -> bf16 hi/lo MFMA A-fragment layout + Kmax ----------
__global__ __launch_bounds__(64) void kprep_kernel(
    const float* __restrict__ keys, unsigned* __restrict__ ctrl,
    uint4* __restrict__ kfg)
{
    const int tile = blockIdx.x;
    const int lane = threadIdx.x;
    const int key  = tile * 32 + (lane & 31);
    const int half = lane >> 5;
    const bool kv  = (key < NKEYS);
    float kmax = 0.f;
#pragma unroll
    for (int ks = 0; ks < 5; ++ks) {
        unsigned wh[4], wl[4];
#pragma unroll
        for (int j = 0; j < 4; ++j) {
            const int l0 = ks * 16 + half * 8 + 2 * j;
            float v0 = (kv && l0     < LL) ? keys[(size_t)key * LL + l0]     : 0.f;
            float v1 = (kv && l0 + 1 < LL) ? keys[(size_t)key * LL + l0 + 1] : 0.f;
            kmax = fmaxf(kmax, fmaxf(fabsf(v0), fabsf(v1)));
            unsigned h0 = bf16rn(v0), h1 = bf16rn(v1);
            float r0 = v0 - __uint_as_float(h0 << 16);
            float r1 = v1 - __uint_as_float(h1 << 16);
            wh[j] = h0 | (h1 << 16);
            wl[j] = bf16rn(r0) | (bf16rn(r1) << 16);
        }
        const int base = tile * 640 + (ks * 2) * 64 + lane;
        kfg[base]      = make_uint4(wh[0], wh[1], wh[2], wh[3]);
        kfg[base + 64] = make_uint4(wl[0], wl[1], wl[2], wl[3]);
    }
#pragma unroll
    for (int m = 32; m >= 1; m >>= 1)
        kmax = fmaxf(kmax, __shfl_xor(kmax, m));
    if (lane == 0) atomicMax(&ctrl[1], __float_as_uint(kmax));
}

// ---------------- route helpers ----------------
__device__ __forceinline__ void build_qfrag(
    const float* __restrict__ qp, int hv, FU* qh, FU* ql, float& Ssum)
{
    Ssum = 0.f;
#pragma unroll
    for (int ks = 0; ks < 5; ++ks) {
        unsigned wh[4], wl[4];
#pragma unroll
        for (int j = 0; j < 4; ++j) {
            const int l0 = ks * 16 + hv * 8 + 2 * j;
            float v0 = (l0     < LL) ? qp[(size_t)l0 * HW]       : 0.f;
            float v1 = (l0 + 1 < LL) ? qp[(size_t)(l0 + 1) * HW] : 0.f;
            Ssum += fabsf(v0) + fabsf(v1);
            unsigned h0 = bf16rn(v0), h1 = bf16rn(v1);
            float r0 = v0 - __uint_as_float(h0 << 16);
            float r1 = v1 - __uint_as_float(h1 << 16);
            wh[j] = h0 | (h1 << 16);
            wl[j] = bf16rn(r0) | (bf16rn(r1) << 16);
        }
        qh[ks].u4 = make_uint4(wh[0], wh[1], wh[2], wh[3]);
        ql[ks].u4 = make_uint4(wl[0], wl[1], wl[2], wl[3]);
    }
}

// one K-tile x two pixel-sets; exact f32 top-2 via med3
template<bool LAST>
__device__ __forceinline__ void do_tile2(
    const uint4* __restrict__ kb, int t, int tileIdx,
    const FU* __restrict__ qhA, const FU* __restrict__ qlA,
    const FU* __restrict__ qhB, const FU* __restrict__ qlB,
    int lane, int hb,
    float& b1A, float& b2A, int& biA,
    float& b1B, float& b2B, int& biB)
{
    f16v accA, accB;
#pragma unroll
    for (int r = 0; r < 16; ++r) { accA[r] = 0.f; accB[r] = 0.f; }
#pragma unroll
    for (int ks = 0; ks < 5; ++ks) {
        FU kh, kl;
        kh.u4 = kb[(t * 5 + ks) * 128 + lane];
        kl.u4 = kb[(t * 5 + ks) * 128 + 64 + lane];
        accA = __builtin_amdgcn_mfma_f32_32x32x16_bf16(kh.v, qhA[ks].v, accA, 0, 0, 0);
        accB = __builtin_amdgcn_mfma_f32_32x32x16_bf16(kh.v, qhB[ks].v, accB, 0, 0, 0);
        accA = __builtin_amdgcn_mfma_f32_32x32x16_bf16(kh.v, qlA[ks].v, accA, 0, 0, 0);
        accB = __builtin_amdgcn_mfma_f32_32x32x16_bf16(kh.v, qlB[ks].v, accB, 0, 0, 0);
        accA = __builtin_amdgcn_mfma_f32_32x32x16_bf16(kl.v, qhA[ks].v, accA, 0, 0, 0);
        accB = __builtin_amdgcn_mfma_f32_32x32x16_bf16(kl.v, qhB[ks].v, accB, 0, 0, 0);
    }
    const int kb0 = tileIdx * 32 + hb;
    const int NR = LAST ? 12 : 16;   // last tile: rows >=24 are pad keys
#pragma unroll
    for (int r = 0; r < NR; ++r) {
        const int key = kb0 + ((r & 3) + 8 * (r >> 2));
        {
            const float s = accA[r];
            const float n2 = __builtin_amdgcn_fmed3f(b1A, b2A, s); // exact 2nd-max
            const bool gt = (s > b1A);
            b1A = fmaxf(b1A, s); b2A = n2; biA = gt ? key : biA;
        }
        {
            const float s = accB[r];
            const float n2 = __builtin_amdgcn_fmed3f(b1B, b2B, s);
            const bool gt = (s > b1B);
            b1B = fmaxf(b1B, s); b2B = n2; biB = gt ? key : biB;
        }
    }
}

// grid = (NPIX/256, NSPL) x 256 threads. Wave = 64 pixels (2 sets of 32).
__global__ __launch_bounds__(256, 2) void route_kernel(
    const float* __restrict__ queries,
    const uint4* __restrict__ kfg,
    const unsigned* __restrict__ ctrl,
    float* __restrict__ b1s, float* __restrict__ b2s,
    int* __restrict__ bis, float* __restrict__ thr)
{
    __shared__ uint4 kbuf[2][1280];   // double-buffered group of 2 tiles (40 KB)

    const int tid   = threadIdx.x;
    const int lane  = tid & 63;
    const int wid   = tid >> 6;
    const int hv    = lane >> 5;      // k-half
    const int hb    = 4 * hv;
    const int split = blockIdx.y;
    const int pA = blockIdx.x * 256 + wid * 64 + (lane & 31);
    const int pB = pA + 32;

    FU qhA[5], qlA[5], qhB[5], qlB[5];
    float SsA, SsB;
    {
        const int bA = pA / HW, hwA = pA - bA * HW;
        build_qfrag(queries + (size_t)bA * LL * HW + hwA, hv, qhA, qlA, SsA);
        const int bB = pB / HW, hwB = pB - bB * HW;
        build_qfrag(queries + (size_t)bB * LL * HW + hwB, hv, qhB, qlB, SsB);
    }

    float b1A = -3.0e38f, b2A = -3.0e38f; int biA = 0;
    float b1B = -3.0e38f, b2B = -3.0e38f; int biB = 0;

    const int t0 = split * 24;
    const int ng = (split == NSPL - 1) ? 11 : 12;   // tiles: 24,24,24,22 (all even)

#pragma unroll
    for (int j = 0; j < 5; ++j)
        kbuf[0][tid + j * 256] = kfg[(size_t)t0 * 640 + tid + j * 256];
    __syncthreads();

    for (int g = 0; g < ng; ++g) {
        const int cur = g & 1;
        if (g < ng - 1) {
#pragma unroll
            for (int j = 0; j < 5; ++j)
                kbuf[cur ^ 1][tid + j * 256] =
                    kfg[(size_t)(t0 + 2 * (g + 1)) * 640 + tid + j * 256];
        }
        const uint4* kb = kbuf[cur];
        const int base = t0 + 2 * g;
        do_tile2<false>(kb, 0, base, qhA, qlA, qhB, qlB, lane, hb,
                        b1A, b2A, biA, b1B, b2B, biB);
        if (base + 1 == NT - 1)
            do_tile2<true >(kb, 1, base + 1, qhA, qlA, qhB, qlB, lane, hb,
                            b1A, b2A, biA, b1B, b2B, biB);
        else
            do_tile2<false>(kb, 1, base + 1, qhA, qlA, qhB, qlB, lane, hb,
                            b1A, b2A, biA, b1B, b2B, biB);
        __syncthreads();
    }

    // merge k-halves (lane <-> lane+32 hold the same pixel, disjoint keys)
    const float o1A = __shfl_xor(b1A, 32), o2A = __shfl_xor(b2A, 32);
    const int   oiA = __shfl_xor(biA, 32);
    const float n2A = fmaxf(fminf(b1A, o1A), fmaxf(b2A, o2A));
    const bool  tkA = (o1A > b1A) || (o1A == b1A && oiA < biA);
    const float n1A = fmaxf(b1A, o1A);
    const int   niA = tkA ? oiA : biA;

    const float o1B = __shfl_xor(b1B, 32), o2B = __shfl_xor(b2B, 32);
    const int   oiB = __shfl_xor(biB, 32);
    const float n2B = fmaxf(fminf(b1B, o1B), fmaxf(b2B, o2B));
    const bool  tkB = (o1B > b1B) || (o1B == b1B && oiB < biB);
    const float n1B = fmaxf(b1B, o1B);
    const int   niB = tkB ? oiB : biB;

    if ((lane & 32) == 0) {
        const int sp = split * NPIX;
        b1s[sp + pA] = n1A; b2s[sp + pA] = n2A; bis[sp + pA] = niA;
        b1s[sp + pB] = n1B; b2s[sp + pB] = n2B; bis[sp + pB] = niB;
        if (split == 0) {
            const float kmax = __uint_as_float(ctrl[1]);
            const float SpA = SsA + __shfl_xor(SsA, 32);
            const float SpB = SsB + __shfl_xor(SsB, 32);
            thr[pA] = 2.0f * (CERR * SpA * kmax + ABSG);
            thr[pB] = 2.0f * (CERR * SpB * kmax + ABSG);
        }
    }
}

// ------ combine: exact cross-split top-2 merge + certainty routing ------
__global__ __launch_bounds__(256) void combine_kernel(
    const float* __restrict__ b1s, const float* __restrict__ b2s,
    const int* __restrict__ bis, const float* __restrict__ thr,
    unsigned* __restrict__ ctrl, unsigned* __restrict__ list,
    int* __restrict__ idx_buf)
{
    const int p = blockIdx.x * 256 + threadIdx.x;
    float m1 = -3.0e38f, m2 = -3.0e38f; int bi = 0;
#pragma unroll
    for (int s = 0; s < NSPL; ++s) {
        const float a1 = b1s[s * NPIX + p];
        const float a2 = b2s[s * NPIX + p];
        const int   ai = bis[s * NPIX + p];
        if (a1 > m1) { m2 = fmaxf(m1, a2); m1 = a1; bi = ai; }  // splits ascend in key
        else         { m2 = fmaxf(m2, a1); }
    }
    if ((m1 - m2) > thr[p]) idx_buf[p] = bi;
    else { unsigned pos = atomicAdd(&ctrl[0], 1u); list[pos] = (unsigned)p; }
}

// -------- cleanup: exact f32 rescore, one BLOCK per uncertain pixel --------
__global__ __launch_bounds__(256) void cleanup_kernel(
    const float* __restrict__ queries, const float* __restrict__ keys,
    const unsigned* __restrict__ ctrl, const unsigned* __restrict__ list,
    int* __restrict__ idx_buf)
{
    __shared__ float qs[LL];
    __shared__ float rbest[4];
    __shared__ int   ridx[4];

    const int tid = threadIdx.x;
    const int ln  = tid & 63;
    const int wid = tid >> 6;
    const unsigned count = ctrl[0];

    for (unsigned u = blockIdx.x; u < count; u += gridDim.x) {
        const int p  = (int)list[u];
        const int b  = p / HW;
        const int hw = p - b * HW;

        __syncthreads();
        if (tid < LL)
            qs[tid] = queries[((size_t)b * LL + tid) * HW + hw];
        __syncthreads();

        float q[LL];
#pragma unroll
        for (int l = 0; l < LL; ++l) q[l] = qs[l];

        float best = -3.0e38f; int bidx = 0x7FFFFFFF;
#pragma unroll 1
        for (int it = 0; it < 12; ++it) {
            const int n  = it * 256 + tid;
            const int nc = (n < NKEYS) ? n : (NKEYS - 1);
            const float4* __restrict__ kr = (const float4*)(keys + (size_t)nc * LL);
            float a0 = 0.f, a1 = 0.f, a2 = 0.f, a3 = 0.f;
#pragma unroll
            for (int j = 0; j < 18; ++j) {
                float4 kv = kr[j];
                a0 = fmaf(q[4 * j + 0], kv.x, a0);
                a1 = fmaf(q[4 * j + 1], kv.y, a1);
                a2 = fmaf(q[4 * j + 2], kv.z, a2);
                a3 = fmaf(q[4 * j + 3], kv.w, a3);
            }
            const float s = (a0 + a1) + (a2 + a3);
            if (n < NKEYS && (s > best || (s == best && n < bidx))) { best = s; bidx = n; }
        }
#pragma unroll
        for (int m = 32; m >= 1; m >>= 1) {
            const float ob = __shfl_xor(best, m);
            const int   oi = __shfl_xor(bidx, m);
            if (ob > best || (ob == best && oi < bidx)) { best = ob; bidx = oi; }
        }
        if (ln == 0) { rbest[wid] = best; ridx[wid] = bidx; }
        __syncthreads();
        if (tid == 0) {
            float fb = rbest[0]; int fi = ridx[0];
#pragma unroll
            for (int wvi = 1; wvi < 4; ++wvi) {
                if (rbest[wvi] > fb || (rbest[wvi] == fb && ridx[wvi] < fi)) {
                    fb = rbest[wvi]; fi = ridx[wvi];
                }
            }
            idx_buf[p] = fi;
        }
    }
}

// ------- conv: gather + dynamic 5x5 conv + pixel shuffle -------
__global__ __launch_bounds__(256) void conv_kernel(
    const float* __restrict__ x,
    const float* __restrict__ values,
    const int* __restrict__ idx_buf,
    float* __restrict__ out)
{
    const int p  = blockIdx.x * 256 + threadIdx.x;
    const int b  = p / HW;
    const int hw = p - b * HW;
    const int h  = hw / W;
    const int w  = hw - h * W;

    const int idx = idx_buf[p];

    float patch[CC][25];
#pragma unroll
    for (int i = 0; i < 5; ++i) {
        int r = h + i - 2;
        r = (r < 0) ? -r : ((r >= H) ? (2 * H - 2 - r) : r);
#pragma unroll
        for (int j = 0; j < 5; ++j) {
            int cidx = w + j - 2;
            cidx = (cidx < 0) ? -cidx : ((cidx >= W) ? (2 * W - 2 - cidx) : cidx);
#pragma unroll
            for (int c = 0; c < CC; ++c)
                patch[c][i * 5 + j] = x[((size_t)(b * CC + c) * H + r) * W + cidx];
        }
    }

    const float* vbase = values + (size_t)idx * 400;
    float acc[CC][16];
#pragma unroll
    for (int c = 0; c < CC; ++c)
#pragma unroll
        for (int si = 0; si < 16; ++si) acc[c][si] = 0.f;

#pragma unroll
    for (int si = 0; si < 16; ++si) {
        float v[25];
#pragma unroll
        for (int kk = 0; kk < 25; ++kk) v[kk] = vbase[si * 25 + kk];
#pragma unroll
        for (int c = 0; c < CC; ++c) {
            float a = 0.f;
#pragma unroll
            for (int kk = 0; kk < 25; ++kk) a += patch[c][kk] * v[kk];
            acc[c][si] = a;
        }
    }

#pragma unroll
    for (int c = 0; c < CC; ++c) {
#pragma unroll
        for (int sy = 0; sy < 4; ++sy) {
            float4 o = make_float4(acc[c][sy * 4 + 0], acc[c][sy * 4 + 1],
                                   acc[c][sy * 4 + 2], acc[c][sy * 4 + 3]);
            size_t off = ((size_t)(b * CC + c) * (H * 4) + (h * 4 + sy)) * (size_t)(W * 4)
                         + (size_t)w * 4;
            *(float4*)(&out[off]) = o;
        }
    }
}

extern "C" void kernel_launch(void* const* d_in, const int* in_sizes, int n_in,
                              void* d_out, int out_size, void* d_ws, size_t ws_size,
                              hipStream_t stream) {
    const float* x       = (const float*)d_in[0];
    const float* queries = (const float*)d_in[1];
    const float* keys    = (const float*)d_in[2];
    const float* values  = (const float*)d_in[3];
    float* out = (float*)d_out;

    char* ws = (char*)d_ws;
    unsigned* ctrl = (unsigned*)ws;
    uint4*    kfg  = (uint4*)(ws + WS_KFRAG);
    float*    b1s  = (float*)(ws + WS_B1);
    float*    b2s  = (float*)(ws + WS_B2);
    int*      bis  = (int*)(ws + WS_BI);
    float*    thr  = (float*)(ws + WS_THR);
    unsigned* list = (unsigned*)(ws + WS_LIST);
    int*      idxb = (int*)(ws + WS_IDX);

    hipMemsetAsync(d_ws, 0, 8, stream);
    kprep_kernel<<<NT, 64, 0, stream>>>(keys, ctrl, kfg);
    route_kernel<<<dim3(NPIX / 256, NSPL), 256, 0, stream>>>(queries, kfg, ctrl,
                                                             b1s, b2s, bis, thr);
    combine_kernel<<<NPIX / 256, 256, 0, stream>>>(b1s, b2s, bis, thr, ctrl, list, idxb);
    cleanup_kernel<<<2048, 256, 0, stream>>>(queries, keys, ctrl, list, idxb);
    conv_kernel<<<NPIX / 256, 256, 0, stream>>>(x, values, idxb, out);
}